// Round 17
// baseline (509.511 us; speedup 1.0000x reference)
//
#include <hip/hip_runtime.h>
#include <stdint.h>

typedef unsigned short u16;
typedef _Float16 f16x8 __attribute__((ext_vector_type(8)));
typedef float f32x4 __attribute__((ext_vector_type(4)));

#define AS1C const __attribute__((address_space(1))) void*
#define AS3P __attribute__((address_space(3))) void*

#define DM 1024
#define DI 2048
#define CHN 2176
#define ROWS 4096
#define PADR_U 2051   // 3 pad rows + 2048 per batch, width 1024

__device__ __forceinline__ float h2f(u16 v) {
    union { u16 u; _Float16 h; } x; x.u = v; return (float)x.h;
}
__device__ __forceinline__ u16 f2h(float f) {
    union { _Float16 h; u16 u; } x; x.h = (_Float16)f; return x.u;
}

// ---------- single-f16 MFMA GEMM (m97 structure + XOR swizzle, R12-proven) ----------
// ASRC: 0 plain NT (ld=ldA), 1 implicit im2col over padded-u rows
// EPI : 0 fp32 store (ldC), 3 f16 store to Wbig, 4 f16 partial store (split-K)
template<int ASRC, int EPI>
__global__ __launch_bounds__(256) void split_gemm(
    const u16* __restrict__ Ah, const u16* __restrict__ Bh,
    float* __restrict__ Cf, u16* __restrict__ Oh,
    int K, int ldA, int ldB, int ldC, int aoffR, int kbase)
{
    __shared__ u16 Ash[128 * 64];
    __shared__ u16 Bsh[128 * 64];
    const int tid = threadIdx.x;
    const int bm = blockIdx.x * 128;
    const int bn = blockIdx.y * 128;
    const int lane = tid & 63;
    const int w = tid >> 6, wr = w >> 1, wc = w & 1;
    const int lrow = lane & 15;
    const int cb = lane >> 4;
    const int trow = tid >> 3;
    const int tcolS = (((tid & 7) ^ (trow & 7)) << 3);

    f32x4 acc[4][4];
#pragma unroll
    for (int m = 0; m < 4; ++m)
#pragma unroll
        for (int n = 0; n < 4; ++n) acc[m][n] = f32x4{0.f, 0.f, 0.f, 0.f};

    for (int kq = 0; kq < K; kq += 64) {
        int k0 = kbase + kq;
#pragma unroll
        for (int ch = 0; ch < 4; ++ch) {
            int r = bm + ch * 32 + trow;
            long aoff;
            if (ASRC == 1) {
                int kc = k0 >> 10;            // 1024 % 64 == 0: no straddle
                int i0 = k0 & 1023;
                long srow = (long)(r >> 11) * PADR_U + (r & 2047) + kc + aoffR;
                aoff = srow * 1024 + i0 + tcolS;
            } else {
                aoff = (long)r * ldA + k0 + tcolS;
            }
            __builtin_amdgcn_global_load_lds((AS1C)(Ah + aoff), (AS3P)(&Ash[ch * 2048 + tid * 8]), 16, 0, 0);
            int rr = bn + ch * 32 + trow;
            long boff = (long)rr * ldB + k0 + tcolS;
            __builtin_amdgcn_global_load_lds((AS1C)(Bh + boff), (AS3P)(&Bsh[ch * 2048 + tid * 8]), 16, 0, 0);
        }
        __syncthreads();
#pragma unroll
        for (int kk = 0; kk < 64; kk += 32) {
            const int swz = ((((kk >> 3) + cb) ^ (lrow & 7)) << 3);
            f16x8 a[4], b[4];
#pragma unroll
            for (int m = 0; m < 4; ++m)
                a[m] = *(const f16x8*)&Ash[(wr * 64 + m * 16 + lrow) * 64 + swz];
#pragma unroll
            for (int n = 0; n < 4; ++n)
                b[n] = *(const f16x8*)&Bsh[(wc * 64 + n * 16 + lrow) * 64 + swz];
#pragma unroll
            for (int m = 0; m < 4; ++m)
#pragma unroll
                for (int n = 0; n < 4; ++n)
                    acc[m][n] = __builtin_amdgcn_mfma_f32_16x16x32_f16(a[m], b[n], acc[m][n], 0, 0, 0);
        }
        __syncthreads();
    }

#pragma unroll
    for (int m = 0; m < 4; ++m) {
#pragma unroll
        for (int n = 0; n < 4; ++n) {
            int col = bn + wc * 64 + n * 16 + lrow;
            int rbase = bm + wr * 64 + m * 16 + ((lane >> 4) << 2);
#pragma unroll
            for (int j = 0; j < 4; ++j) {
                int r = rbase + j;
                float v = acc[m][n][j];
                if (EPI == 0) {
                    Cf[(long)r * ldC + col] = v;
                } else if (EPI == 3) {
                    int kc = r / CHN;           // r = kc*2176 + o
                    int o = r - kc * CHN;
                    Oh[(long)o * 4096 + kc * 1024 + col] = f2h(v);
                } else {
                    Oh[(long)r * CHN + col] = f2h(v);   // partial
                }
            }
        }
    }
}

// split-K conv wrapper: z = blockIdx.z selects K-half and partial buffer
__global__ __launch_bounds__(256) void conv_splitk(
    const u16* __restrict__ up, const u16* __restrict__ Wbig,
    u16* __restrict__ P0, u16* __restrict__ P1)
{
    __shared__ u16 Ash[128 * 64];
    __shared__ u16 Bsh[128 * 64];
    const int tid = threadIdx.x;
    const int bm = blockIdx.x * 128;
    const int bn = blockIdx.y * 128;
    const int z = blockIdx.z;
    const int kbase = z * 2048;
    u16* __restrict__ P = z ? P1 : P0;
    const int lane = tid & 63;
    const int w = tid >> 6, wr = w >> 1, wc = w & 1;
    const int lrow = lane & 15;
    const int cb = lane >> 4;
    const int trow = tid >> 3;
    const int tcolS = (((tid & 7) ^ (trow & 7)) << 3);

    f32x4 acc[4][4];
#pragma unroll
    for (int m = 0; m < 4; ++m)
#pragma unroll
        for (int n = 0; n < 4; ++n) acc[m][n] = f32x4{0.f, 0.f, 0.f, 0.f};

    for (int kq = 0; kq < 2048; kq += 64) {
        int k0 = kbase + kq;
        const int kc = k0 >> 10;
        const int i0 = k0 & 1023;
#pragma unroll
        for (int ch = 0; ch < 4; ++ch) {
            int r = bm + ch * 32 + trow;
            long srow = (long)(r >> 11) * PADR_U + (r & 2047) + kc;
            long aoff = srow * 1024 + i0 + tcolS;
            __builtin_amdgcn_global_load_lds((AS1C)(up + aoff), (AS3P)(&Ash[ch * 2048 + tid * 8]), 16, 0, 0);
            int rr = bn + ch * 32 + trow;
            long boff = (long)rr * 4096 + k0 + tcolS;
            __builtin_amdgcn_global_load_lds((AS1C)(Wbig + boff), (AS3P)(&Bsh[ch * 2048 + tid * 8]), 16, 0, 0);
        }
        __syncthreads();
#pragma unroll
        for (int kk = 0; kk < 64; kk += 32) {
            const int swz = ((((kk >> 3) + cb) ^ (lrow & 7)) << 3);
            f16x8 a[4], b[4];
#pragma unroll
            for (int m = 0; m < 4; ++m)
                a[m] = *(const f16x8*)&Ash[(wr * 64 + m * 16 + lrow) * 64 + swz];
#pragma unroll
            for (int n = 0; n < 4; ++n)
                b[n] = *(const f16x8*)&Bsh[(wc * 64 + n * 16 + lrow) * 64 + swz];
#pragma unroll
            for (int m = 0; m < 4; ++m)
#pragma unroll
                for (int n = 0; n < 4; ++n)
                    acc[m][n] = __builtin_amdgcn_mfma_f32_16x16x32_f16(a[m], b[n], acc[m][n], 0, 0, 0);
        }
        __syncthreads();
    }

#pragma unroll
    for (int m = 0; m < 4; ++m) {
#pragma unroll
        for (int n = 0; n < 4; ++n) {
            int col = bn + wc * 64 + n * 16 + lrow;
            int rbase = bm + wr * 64 + m * 16 + ((lane >> 4) << 2);
#pragma unroll
            for (int j = 0; j < 4; ++j) {
                int r = rbase + j;
                P[(long)r * CHN + col] = f2h(acc[m][n][j]);
            }
        }
    }
}

// reduce partials + bias + prelu + split
__global__ __launch_bounds__(256) void conv_reduce(
    const u16* __restrict__ P0, const u16* __restrict__ P1,
    float* __restrict__ Xf, float* __restrict__ Bm, float* __restrict__ Cm,
    const float* __restrict__ bias, const float* __restrict__ prelu)
{
    const long idx = (long)blockIdx.x * 256 + threadIdx.x;   // u16x8 units
    if (idx >= (long)ROWS * CHN / 8) return;
    const long e0 = idx * 8;
    const int r = (int)(e0 / CHN);
    const int col = (int)(e0 - (long)r * CHN);
    const float pa = *prelu;
    f16x8 a = *(const f16x8*)&P0[e0];
    f16x8 b = *(const f16x8*)&P1[e0];
    float v[8];
#pragma unroll
    for (int j = 0; j < 8; ++j) {
        float x = (float)a[j] + (float)b[j] + bias[col + j];
        v[j] = x > 0.f ? x : pa * x;
    }
    if (col < DI) {
        f32x4 o0 = {v[0], v[1], v[2], v[3]};
        f32x4 o1 = {v[4], v[5], v[6], v[7]};
        *(f32x4*)&Xf[(long)r * DI + col] = o0;
        *(f32x4*)&Xf[(long)r * DI + col + 4] = o1;
    } else if (col < DI + 64) {
        f32x4 o0 = {v[0], v[1], v[2], v[3]};
        f32x4 o1 = {v[4], v[5], v[6], v[7]};
        *(f32x4*)&Bm[r * 64 + (col - DI)] = o0;
        *(f32x4*)&Bm[r * 64 + (col - DI) + 4] = o1;
    } else {
        f32x4 o0 = {v[0], v[1], v[2], v[3]};
        f32x4 o1 = {v[4], v[5], v[6], v[7]};
        *(f32x4*)&Cm[r * 64 + (col - DI - 64)] = o0;
        *(f32x4*)&Cm[r * 64 + (col - DI - 64) + 4] = o1;
    }
}

// ---------------- prep kernels ----------------
__global__ void conv_w_h(const float* __restrict__ w, u16* __restrict__ ch_) {
    int idx = blockIdx.x * 256 + threadIdx.x;
    if (idx < CHN * CHN) {
        int o = idx / CHN, i = idx - o * CHN;
        f32x4 v = *(const f32x4*)&w[(long)idx * 4];
#pragma unroll
        for (int kc = 0; kc < 4; ++kc)
            ch_[(long)(kc * CHN + o) * CHN + i] = f2h(v[kc]);
    }
}

__global__ __launch_bounds__(256) void w1x_t(
    const float* __restrict__ W1, u16* __restrict__ th)
{
    __shared__ float tile[32][33];
    int i0 = blockIdx.x * 32, d0 = blockIdx.y * 32;
    int ti = threadIdx.x & 31, tj = threadIdx.x >> 5;
#pragma unroll
    for (int rr = 0; rr < 32; rr += 8)
        tile[tj + rr][ti] = W1[(long)(2048 + i0 + tj + rr) * 1024 + d0 + ti];
    __syncthreads();
#pragma unroll
    for (int rr = 0; rr < 32; rr += 8)
        th[(long)(d0 + tj + rr) * CHN + i0 + ti] = f2h(tile[ti][tj + rr]);
}

// fused u-pad (f16) + dt (fp32 softplus A_t).  One block = 8 u-rows.
__global__ __launch_bounds__(256) void u_pad_dt(
    const float* __restrict__ u, const float* __restrict__ W1,
    const float* __restrict__ A_log, u16* __restrict__ ph, float* __restrict__ A_t)
{
    __shared__ float us[8][1024];
    int r0 = blockIdx.x * 8;
    int tid = threadIdx.x;
#pragma unroll
    for (int rep = 0; rep < 8; ++rep) {
        int idx = rep * 256 + tid;
        int i = idx >> 8, kx = (idx & 255) << 2;
        *(f32x4*)&us[i][kx] = *(const f32x4*)&u[(long)(r0 + i) * 1024 + kx];
    }
    __syncthreads();
#pragma unroll
    for (int rep = 0; rep < 8; ++rep) {
        int idx = rep * 256 + tid;
        int i = idx >> 8, kx = (idx & 255) << 2;
        int r = r0 + i;
        long prow = (long)(r >> 11) * PADR_U + 3 + (r & 2047);
        f32x4 v = *(const f32x4*)&us[i][kx];
        ushort4 h;
        h.x = f2h(v[0]); h.y = f2h(v[1]); h.z = f2h(v[2]); h.w = f2h(v[3]);
        *(ushort4*)&ph[prow * 1024 + kx] = h;
    }
    int row = tid >> 5;
    int hh = tid & 31;
    const float* wrow = W1 + (long)(4224 + hh) * 1024;
    f32x4 a4 = {0.f, 0.f, 0.f, 0.f};
#pragma unroll 4
    for (int k = 0; k < 1024; k += 4) {
        f32x4 a = *(const f32x4*)&us[row][k];
        f32x4 b = *(const f32x4*)&wrow[k];
        a4 += a * b;
    }
    float dt = a4[0] + a4[1] + a4[2] + a4[3];
    if (dt <= 20.f) dt = log1pf(__expf(dt));
    float At = dt * (-__expf(A_log[hh]));
    int r = r0 + row;
    int b = r >> 11, l = r & 2047;
    A_t[((long)(b * 32 + hh)) * 2048 + l] = At;
}

__global__ void zero_pad_u(u16* __restrict__ ph) {
    int t = blockIdx.x * 256 + threadIdx.x;
    if (t < 3 * 1024) {
        ph[t] = 0;
        ph[(long)PADR_U * 1024 + t] = 0;
    }
}

__global__ void cast2_f16(const float* __restrict__ a, u16* __restrict__ oa,
                          const float* __restrict__ b, u16* __restrict__ ob, int n4) {
    int idx = blockIdx.x * 256 + threadIdx.x;
    const float* src;
    u16* dst;
    if (idx < n4) { src = a; dst = oa; }
    else if (idx < 2 * n4) { idx -= n4; src = b; dst = ob; }
    else return;
    f32x4 v = *(const f32x4*)&src[(long)idx * 4];
    ushort4 h;
    h.x = f2h(v[0]); h.y = f2h(v[1]); h.z = f2h(v[2]); h.w = f2h(v[3]);
    *(ushort4*)&dst[(long)idx * 4] = h;
}

// ---------------- chunked SSD (bl = 128, c = 16) ----------------
__global__ __launch_bounds__(256) void csum_g(
    float* A_t, float* __restrict__ Atot,
    const float* __restrict__ Cm, const float* __restrict__ Bm, float* __restrict__ G)
{
    if (blockIdx.x < 1024) {
        if (threadIdx.x >= 64) return;
        int bid = blockIdx.x;
        int lane = threadIdx.x;
        float* p = A_t + (long)bid * 128;
        float v0 = p[lane * 2], v1 = p[lane * 2 + 1];
        float s = v0 + v1;
        float t = s;
#pragma unroll
        for (int d = 1; d < 64; d <<= 1) {
            float o = __shfl_up(t, d);
            if (lane >= d) t += o;
        }
        float excl = t - s;
        p[lane * 2] = excl + v0;
        p[lane * 2 + 1] = excl + s;
        if (lane == 63) Atot[bid] = t;
        return;
    }
    __shared__ float CsT[128 * 33];
    __shared__ float BsT[128 * 33];
    const int bid = blockIdx.x - 1024;   // b*16 + c
    const int b = bid >> 4, c = bid & 15;
    const long rowbase = (long)b * 2048 + c * 128;
    const int tid = threadIdx.x;
    const int li = tid & 15, si = tid >> 4;
    const int l0 = li * 8, s0 = si * 8;
    float acc[8][8];
#pragma unroll
    for (int i = 0; i < 8; ++i)
#pragma unroll
        for (int j = 0; j < 8; ++j) acc[i][j] = 0.f;

    for (int kt = 0; kt < 2; ++kt) {
        __syncthreads();
#pragma unroll
        for (int t = 0; t < 16; ++t) {
            int idx = t * 256 + tid;
            int row = idx >> 5, k = idx & 31;
            CsT[row * 33 + k] = Cm[(rowbase + row) * 64 + kt * 32 + k];
            BsT[row * 33 + k] = Bm[(rowbase + row) * 64 + kt * 32 + k];
        }
        __syncthreads();
        for (int k = 0; k < 32; ++k) {
            float cv[8], bv[8];
#pragma unroll
            for (int i = 0; i < 8; ++i) cv[i] = CsT[(l0 + i) * 33 + k];
#pragma unroll
            for (int j = 0; j < 8; ++j) bv[j] = BsT[(s0 + j) * 33 + k];
#pragma unroll
            for (int i = 0; i < 8; ++i)
#pragma unroll
                for (int j = 0; j < 8; ++j) acc[i][j] += cv[i] * bv[j];
        }
    }
    float* gz = G + (long)bid * 16384;
#pragma unroll
    for (int i = 0; i < 8; ++i) {
        f32x4 o0 = {acc[i][0], acc[i][1], acc[i][2], acc[i][3]};
        f32x4 o1 = {acc[i][4], acc[i][5], acc[i][6], acc[i][7]};
        *(f32x4*)&gz[(l0 + i) * 128 + s0] = o0;
        *(f32x4*)&gz[(l0 + i) * 128 + s0 + 4] = o1;
    }
}

// per (b,h,c): Y_diag = (G∘exp(segsum))@X -> XY ; Sc[p,n] = sum_s X[s,p]·exp(T-cs[s])·B[s,n]
__global__ __launch_bounds__(256) void ssd_diag_states(
    float* XY, const float* __restrict__ Bm, const float* __restrict__ G,
    const float* __restrict__ cs, const float* __restrict__ Atot, float* __restrict__ Sc)
{
    __shared__ float Xs[128 * 64];
    __shared__ float Gb[32 * 132];
    __shared__ float csL[128];
    __shared__ float dsL[128];
    const int bid = blockIdx.x;
    const int bh = bid >> 4, c = bid & 15;
    const int b = bh >> 5, h = bh & 31;
    const long rowbase = (long)b * 2048 + c * 128;
    const float* gz = G + (long)(b * 16 + c) * 16384;
    const float atot = Atot[bid];
    const int tid = threadIdx.x;

    if (tid < 128) csL[tid] = cs[(long)bh * 2048 + c * 128 + tid];
#pragma unroll
    for (int t = 0; t < 8; ++t) {
        int idx = t * 256 + tid;
        int row = idx >> 4, c4 = (idx & 15) << 2;
        *(f32x4*)&Xs[row * 64 + c4] = *(const f32x4*)&XY[(rowbase + row) * 2048 + h * 64 + c4];
    }
    __syncthreads();
    if (tid < 128) dsL[tid] = __expf(atot - csL[tid]);

    const int lg = tid & 31, pg = tid >> 5;
    const int l0 = lg * 4, p0 = pg * 8;
    float cl[4];
#pragma unroll
    for (int i = 0; i < 4; ++i) cl[i] = csL[l0 + i];
    float acc1[4][8];
#pragma unroll
    for (int i = 0; i < 4; ++i)
#pragma unroll
        for (int j = 0; j < 8; ++j) acc1[i][j] = 0.f;

    for (int st = 0; st < 4; ++st) {
        __syncthreads();
#pragma unroll
        for (int t = 0; t < 16; ++t) {
            int idx = t * 256 + tid;
            int l = idx >> 5, sq = idx & 31;
            Gb[sq * 132 + l] = gz[l * 128 + st * 32 + sq];
        }
        __syncthreads();
        for (int sq = 0; sq < 32; ++sq) {
            int s = st * 32 + sq;
            float css = csL[s];
            f32x4 x0 = *(const f32x4*)&Xs[s * 64 + p0];
            f32x4 x1 = *(const f32x4*)&Xs[s * 64 + p0 + 4];
#pragma unroll
            for (int i = 0; i < 4; ++i) {
                int l = l0 + i;
                float P = (s <= l) ? Gb[sq * 132 + l] * __expf(cl[i] - css) : 0.f;
                acc1[i][0] += P * x0[0]; acc1[i][1] += P * x0[1];
                acc1[i][2] += P * x0[2]; acc1[i][3] += P * x0[3];
                acc1[i][4] += P * x1[0]; acc1[i][5] += P * x1[1];
                acc1[i][6] += P * x1[2]; acc1[i][7] += P * x1[3];
            }
        }
    }

    const int pq = tid & 15, nq = tid >> 4;
    const int pp0 = pq * 4, nn0 = nq * 4;
    float acc2[4][4];
#pragma unroll
    for (int i = 0; i < 4; ++i)
#pragma unroll
        for (int j = 0; j < 4; ++j) acc2[i][j] = 0.f;
    for (int half = 0; half < 2; ++half) {
        __syncthreads();
#pragma unroll
        for (int t = 0; t < 4; ++t) {
            int idx = t * 256 + tid;
            int srow = idx >> 4, c4 = (idx & 15) << 2;
            *(f32x4*)&Gb[srow * 64 + c4] = *(const f32x4*)&Bm[(rowbase + half * 64 + srow) * 64 + c4];
        }
        __syncthreads();
        for (int ss = 0; ss < 64; ++ss) {
            int s = half * 64 + ss;
            float d = dsL[s];
            f32x4 xv = *(const f32x4*)&Xs[s * 64 + pp0];
            f32x4 bv = *(const f32x4*)&Gb[ss * 64 + nn0];
            float xd[4];
#pragma unroll
            for (int i = 0; i < 4; ++i) xd[i] = xv[i] * d;
#pragma unroll
            for (int i = 0; i < 4; ++i)
#pragma unroll
                for (int j = 0; j < 4; ++j) acc2[i][j] += xd[i] * bv[j];
        }
    }
    long scb = (long)bid * 4096;
#pragma unroll
    for (int i = 0; i < 4; ++i) {
        f32x4 o = {acc2[i][0], acc2[i][1], acc2[i][2], acc2[i][3]};
        *(f32x4*)&Sc[scb + (pp0 + i) * 64 + nn0] = o;
    }
#pragma unroll
    for (int i = 0; i < 4; ++i) {
        f32x4 y0 = {acc1[i][0], acc1[i][1], acc1[i][2], acc1[i][3]};
        f32x4 y1 = {acc1[i][4], acc1[i][5], acc1[i][6], acc1[i][7]};
        long yo = (rowbase + l0 + i) * 2048 + h * 64 + p0;
        *(f32x4*)&XY[yo] = y0;
        *(f32x4*)&XY[yo + 4] = y1;
    }
}

// chunk recurrence (in place): Sc[c] -> S_in[c].  grid 256: bh*4 + quarter
__global__ __launch_bounds__(256) void ssd_combine(float* Sc, const float* __restrict__ Atot)
{
    int bh = blockIdx.x >> 2;
    int q = blockIdx.x & 3;
    int tid = threadIdx.x;
    float run[4];
#pragma unroll
    for (int t = 0; t < 4; ++t) run[t] = 0.f;
    for (int c = 0; c < 16; ++c) {
        float e = __expf(Atot[bh * 16 + c]);
        long base = (long)(bh * 16 + c) * 4096 + q * 1024;
#pragma unroll
        for (int t = 0; t < 4; ++t) {
            long idx = base + t * 256 + tid;
            float tmp = Sc[idx];
            Sc[idx] = run[t];
            run[t] = e * run[t] + tmp;
        }
    }
}

// Y += exp(cs[l]) · C[l]·S_in[p]   per (b,h,c)
__global__ __launch_bounds__(256) void ssd_yoff(
    const float* __restrict__ Cm, const float* __restrict__ Sin,
    const float* __restrict__ cs, float* XY)
{
    __shared__ float Cs[128 * 66];
    __shared__ float St[64 * 68];
    __shared__ float csL[128];
    const int bid = blockIdx.x;
    const int bh = bid >> 4, c = bid & 15;
    const int b = bh >> 5, h = bh & 31;
    const long rowbase = (long)b * 2048 + c * 128;
    const int tid = threadIdx.x;

    if (tid < 128) csL[tid] = cs[(long)bh * 2048 + c * 128 + tid];
#pragma unroll
    for (int t = 0; t < 32; ++t) {
        int idx = t * 256 + tid;
        int row = idx >> 6, n = idx & 63;
        Cs[row * 66 + n] = Cm[(rowbase + row) * 64 + n];
    }
#pragma unroll
    for (int t = 0; t < 16; ++t) {
        int idx = t * 256 + tid;
        int p = idx >> 6, n = idx & 63;
        St[n * 68 + p] = Sin[(long)bid * 4096 + p * 64 + n];
    }
    __syncthreads();

    const int lg = tid & 31, pg = tid >> 5;
    const int l0 = lg * 4, p0 = pg * 8;
    float el[4];
#pragma unroll
    for (int i = 0; i < 4; ++i) el[i] = __expf(csL[l0 + i]);
    float acc[4][8];
#pragma unroll
    for (int i = 0; i < 4; ++i)
#pragma unroll
        for (int j = 0; j < 8; ++j) acc[i][j] = 0.f;

    for (int n = 0; n < 64; ++n) {
        float cv[4];
#pragma unroll
        for (int i = 0; i < 4; ++i) cv[i] = Cs[(l0 + i) * 66 + n];
        f32x4 s0 = *(const f32x4*)&St[n * 68 + p0];
        f32x4 s1 = *(const f32x4*)&St[n * 68 + p0 + 4];
#pragma unroll
        for (int i = 0; i < 4; ++i) {
            acc[i][0] += cv[i] * s0[0]; acc[i][1] += cv[i] * s0[1];
            acc[i][2] += cv[i] * s0[2]; acc[i][3] += cv[i] * s0[3];
            acc[i][4] += cv[i] * s1[0]; acc[i][5] += cv[i] * s1[1];
            acc[i][6] += cv[i] * s1[2]; acc[i][7] += cv[i] * s1[3];
        }
    }
#pragma unroll
    for (int i = 0; i < 4; ++i) {
        long yo = (rowbase + l0 + i) * 2048 + h * 64 + p0;
        f32x4 y0 = *(const f32x4*)&XY[yo];
        f32x4 y1 = *(const f32x4*)&XY[yo + 4];
        y0[0] += el[i] * acc[i][0]; y0[1] += el[i] * acc[i][1];
        y0[2] += el[i] * acc[i][2]; y0[3] += el[i] * acc[i][3];
        y1[0] += el[i] * acc[i][4]; y1[1] += el[i] * acc[i][5];
        y1[2] += el[i] * acc[i][6]; y1[3] += el[i] * acc[i][7];
        *(f32x4*)&XY[yo] = y0;
        *(f32x4*)&XY[yo + 4] = y1;
    }
}

// h = gelu(u2raw)*Y ; LayerNorm ; store hn (single f16)
__global__ __launch_bounds__(256) void ln_kernel(
    const float* __restrict__ u2raw, const float* __restrict__ Y,
    const float* __restrict__ lng, const float* __restrict__ lnb,
    u16* __restrict__ hh)
{
    __shared__ float hbuf[2048];
    __shared__ float rs[4], rs2[4];
    int r = blockIdx.x;
    int tid = threadIdx.x;
    float s = 0.f, s2 = 0.f;
    for (int j = tid; j < 2048; j += 256) {
        float x = u2raw[(long)r * 2048 + j];
        float g = 0.5f * x * (1.f + erff(x * 0.70710678118654752f));
        float hv = g * Y[(long)r * 2048 + j];
        hbuf[j] = hv;
        s += hv;
        s2 += hv * hv;
    }
    for (int d = 32; d > 0; d >>= 1) {
        s += __shfl_down(s, d);
        s2 += __shfl_down(s2, d);
    }
    if ((tid & 63) == 0) { rs[tid >> 6] = s; rs2[tid >> 6] = s2; }
    __syncthreads();
    float tot = rs[0] + rs[1] + rs[2] + rs[3];
    float tot2 = rs2[0] + rs2[1] + rs2[2] + rs2[3];
    float mu = tot * (1.f / 2048.f);
    float var = tot2 * (1.f / 2048.f) - mu * mu;
    float inv = rsqrtf(var + 1e-5f);
    for (int j = tid; j < 2048; j += 256) {
        float v = (hbuf[j] - mu) * inv * lng[j] + lnb[j];
        hh[(long)r * 2048 + j] = f2h(v);
    }
}

// ---------------- launcher ----------------
extern "C" void kernel_launch(void* const* d_in, const int* in_sizes, int n_in,
                              void* d_out, int out_size, void* d_ws, size_t ws_size,
                              hipStream_t stream) {
    const float* u = (const float*)d_in[0];
    const float* W1 = (const float*)d_in[1];
    const float* A_log = (const float*)d_in[2];
    const float* convw = (const float*)d_in[3];
    const float* convb = (const float*)d_in[4];
    const float* prelu = (const float*)d_in[5];
    const float* W2 = (const float*)d_in[6];
    const float* W3 = (const float*)d_in[7];
    const float* lng = (const float*)d_in[8];
    const float* lnb = (const float*)d_in[9];
    float* out = (float*)d_out;

    char* base = (char*)d_ws;
    size_t off = 0;
    auto nxt = [&](size_t bytes) -> char* {
        char* r = base + off;
        off = (off + bytes + 255) & ~(size_t)255;
        return r;
    };
    // ~164 MB total
    u16* cw_h = (u16*)nxt((size_t)4 * CHN * CHN * 2);      // 37.9MB, dead after W_eff
    u16* P0 = cw_h;                                         // 17.83MB ┐ partials alias cw
    u16* P1 = cw_h + (size_t)ROWS * CHN;                    // 17.83MB ┘ (35.7 <= 37.9 ✓)
    float* u2raw = (float*)nxt((size_t)ROWS * DI * 4);     // 33.55MB (own)
    u16* up_h = (u16*)nxt((size_t)2 * PADR_U * 1024 * 2);  // 8.40MB
    u16* w1t_h = (u16*)nxt((size_t)1024 * CHN * 2);        // 4.46MB ─┐ Gbuf aliases
    float* Gbuf = (float*)w1t_h;                            // 2.1MB  ─┘ (dead after W_eff)
    u16* wbig_h = (u16*)nxt((size_t)CHN * 4096 * 2);       // 17.83MB
    u16* w2_h = (u16*)nxt((size_t)DI * DM * 2);            // 4.19MB
    u16* w3_h = (u16*)nxt((size_t)DM * DI * 2);            // 4.19MB
    float* A_t = (float*)nxt((size_t)64 * 2048 * 4);       // 0.52MB (chunk csum in place)
    float* Atot = (float*)nxt((size_t)64 * 16 * 4);        // 4KB
    float* XY = (float*)nxt((size_t)ROWS * DI * 4);         // 33.55MB: X -> Y in place
    float* Bmat = (float*)nxt((size_t)ROWS * 64 * 4);      // 1.05MB
    float* Cmat = (float*)nxt((size_t)ROWS * 64 * 4);      // 1.05MB
    float* Sc = (float*)nxt((size_t)64 * 16 * 4096 * 4);   // 16.78MB, dead after yoff
    u16* hn_h = (u16*)Sc;                                   // 16.78MB == span ✓ (LN after yoff)

    // 1. prep
    conv_w_h<<<(CHN * CHN + 255) / 256, 256, 0, stream>>>(convw, cw_h);
    w1x_t<<<dim3(68, 32), 256, 0, stream>>>(W1, w1t_h);
    u_pad_dt<<<512, 256, 0, stream>>>(u, W1, A_log, up_h, A_t);
    zero_pad_u<<<12, 256, 0, stream>>>(up_h);
    cast2_f16<<<(2 * DI * DM / 4 + 255) / 256, 256, 0, stream>>>(
        W2, w2_h, W3, w3_h, DI * DM / 4);

    // 2. W_eff = convw @ W1x (single-f16), store f16 Wbig
    split_gemm<0, 3><<<dim3(68, 8), 256, 0, stream>>>(
        cw_h, w1t_h, nullptr, wbig_h, 2176, 2176, 2176, 0, 0, 0);

    // 3. conv split-K=2: partials (f16, alias dead cw region) + reduce
    conv_splitk<<<dim3(32, 17, 2), 256, 0, stream>>>(up_h, wbig_h, P0, P1);
    conv_reduce<<<(ROWS * CHN / 8 + 255) / 256, 256, 0, stream>>>(
        P0, P1, XY, Bmat, Cmat, convb, prelu);

    // 4. GEMM2: u2raw = u @ W_in2.T
    split_gemm<1, 0><<<dim3(32, 16), 256, 0, stream>>>(
        up_h, w2_h, u2raw, nullptr, 1024, 0, 1024, 2048, 3, 0);

    // 5. chunked SSD (fp32)
    csum_g<<<1056, 256, 0, stream>>>(A_t, Atot, Cmat, Bmat, Gbuf);
    ssd_diag_states<<<1024, 256, 0, stream>>>(XY, Bmat, Gbuf, A_t, Atot, Sc);
    ssd_combine<<<256, 256, 0, stream>>>(Sc, Atot);
    ssd_yoff<<<1024, 256, 0, stream>>>(Cmat, Sc, A_t, XY);

    // 6. h = gelu(u2raw)*Y ; LN -> single f16 hn (aliases Sc — dead)
    ln_kernel<<<4096, 256, 0, stream>>>(u2raw, XY, lng, lnb, hn_h);

    // 7. GEMM3: out = hn @ W_in3.T
    split_gemm<0, 0><<<dim3(32, 8), 256, 0, stream>>>(
        hn_h, w3_h, out, nullptr, 2048, 2048, 2048, 1024, 0, 0);
}

// Round 18
// 484.994 us; speedup vs baseline: 1.0506x; 1.0506x over previous
//
#include <hip/hip_runtime.h>
#include <stdint.h>

typedef unsigned short u16;
typedef _Float16 f16x8 __attribute__((ext_vector_type(8)));
typedef float f32x4 __attribute__((ext_vector_type(4)));

#define AS1C const __attribute__((address_space(1))) void*
#define AS3P __attribute__((address_space(3))) void*

#define DM 1024
#define DI 2048
#define CHN 2176
#define ROWS 4096
#define PADR_U 2051   // 3 pad rows + 2048 per batch, width 1024

__device__ __forceinline__ float h2f(u16 v) {
    union { u16 u; _Float16 h; } x; x.u = v; return (float)x.h;
}
__device__ __forceinline__ u16 f2h(float f) {
    union { _Float16 h; u16 u; } x; x.h = (_Float16)f; return x.u;
}

// ---------- single-f16 MFMA GEMM (m97 structure + XOR swizzle, R12-proven) ----------
// ASRC: 0 plain NT (ld=ldA), 1 implicit im2col over padded-u rows
// EPI : 0 fp32 store (ldC), 2 conv bias+prelu+split X/B/C, 3 f16 store to Wbig
template<int ASRC, int EPI>
__global__ __launch_bounds__(256) void split_gemm(
    const u16* __restrict__ Ah, const u16* __restrict__ Bh,
    float* __restrict__ Cf, float* __restrict__ Bm, float* __restrict__ Cm,
    u16* __restrict__ Oh,
    int K, int ldA, int ldB, int ldC, int aoffR,
    const float* __restrict__ bias, const float* __restrict__ prelu)
{
    __shared__ u16 Ash[128 * 64];
    __shared__ u16 Bsh[128 * 64];
    const int tid = threadIdx.x;
    const int bm = blockIdx.x * 128;
    const int bn = blockIdx.y * 128;
    const int lane = tid & 63;
    const int w = tid >> 6, wr = w >> 1, wc = w & 1;
    const int lrow = lane & 15;
    const int cb = lane >> 4;
    const int trow = tid >> 3;
    const int tcolS = (((tid & 7) ^ (trow & 7)) << 3);

    f32x4 acc[4][4];
#pragma unroll
    for (int m = 0; m < 4; ++m)
#pragma unroll
        for (int n = 0; n < 4; ++n) acc[m][n] = f32x4{0.f, 0.f, 0.f, 0.f};

    for (int k0 = 0; k0 < K; k0 += 64) {
#pragma unroll
        for (int ch = 0; ch < 4; ++ch) {
            int r = bm + ch * 32 + trow;
            long aoff;
            if (ASRC == 1) {
                int kc = k0 >> 10;            // 1024 % 64 == 0: no straddle
                int i0 = k0 & 1023;
                long srow = (long)(r >> 11) * PADR_U + (r & 2047) + kc + aoffR;
                aoff = srow * 1024 + i0 + tcolS;
            } else {
                aoff = (long)r * ldA + k0 + tcolS;
            }
            __builtin_amdgcn_global_load_lds((AS1C)(Ah + aoff), (AS3P)(&Ash[ch * 2048 + tid * 8]), 16, 0, 0);
            int rr = bn + ch * 32 + trow;
            long boff = (long)rr * ldB + k0 + tcolS;
            __builtin_amdgcn_global_load_lds((AS1C)(Bh + boff), (AS3P)(&Bsh[ch * 2048 + tid * 8]), 16, 0, 0);
        }
        __syncthreads();
#pragma unroll
        for (int kk = 0; kk < 64; kk += 32) {
            const int swz = ((((kk >> 3) + cb) ^ (lrow & 7)) << 3);
            f16x8 a[4], b[4];
#pragma unroll
            for (int m = 0; m < 4; ++m)
                a[m] = *(const f16x8*)&Ash[(wr * 64 + m * 16 + lrow) * 64 + swz];
#pragma unroll
            for (int n = 0; n < 4; ++n)
                b[n] = *(const f16x8*)&Bsh[(wc * 64 + n * 16 + lrow) * 64 + swz];
#pragma unroll
            for (int m = 0; m < 4; ++m)
#pragma unroll
                for (int n = 0; n < 4; ++n)
                    acc[m][n] = __builtin_amdgcn_mfma_f32_16x16x32_f16(a[m], b[n], acc[m][n], 0, 0, 0);
        }
        __syncthreads();
    }

    float pa = 0.f;
    if (EPI == 2) pa = *prelu;
#pragma unroll
    for (int m = 0; m < 4; ++m) {
#pragma unroll
        for (int n = 0; n < 4; ++n) {
            int col = bn + wc * 64 + n * 16 + lrow;
            int rbase = bm + wr * 64 + m * 16 + ((lane >> 4) << 2);
            float bv = (EPI == 2) ? bias[col] : 0.f;
#pragma unroll
            for (int j = 0; j < 4; ++j) {
                int r = rbase + j;
                float v = acc[m][n][j];
                if (EPI == 0) {
                    Cf[(long)r * ldC + col] = v;
                } else if (EPI == 3) {
                    int kc = r / CHN;           // r = kc*2176 + o
                    int o = r - kc * CHN;
                    Oh[(long)o * 4096 + kc * 1024 + col] = f2h(v);
                } else {
                    v += bv;
                    v = v > 0.f ? v : pa * v;
                    if (col < DI) Cf[(long)r * DI + col] = v;
                    else if (col < DI + 64) Bm[r * 64 + (col - DI)] = v;
                    else Cm[r * 64 + (col - DI - 64)] = v;
                }
            }
        }
    }
}

// ---------------- prep kernels ----------------
__global__ void conv_w_h(const float* __restrict__ w, u16* __restrict__ ch_) {
    int idx = blockIdx.x * 256 + threadIdx.x;
    if (idx < CHN * CHN) {
        int o = idx / CHN, i = idx - o * CHN;
        f32x4 v = *(const f32x4*)&w[(long)idx * 4];
#pragma unroll
        for (int kc = 0; kc < 4; ++kc)
            ch_[(long)(kc * CHN + o) * CHN + i] = f2h(v[kc]);
    }
}

__global__ __launch_bounds__(256) void w1x_t(
    const float* __restrict__ W1, u16* __restrict__ th)
{
    __shared__ float tile[32][33];
    int i0 = blockIdx.x * 32, d0 = blockIdx.y * 32;
    int ti = threadIdx.x & 31, tj = threadIdx.x >> 5;
#pragma unroll
    for (int rr = 0; rr < 32; rr += 8)
        tile[tj + rr][ti] = W1[(long)(2048 + i0 + tj + rr) * 1024 + d0 + ti];
    __syncthreads();
#pragma unroll
    for (int rr = 0; rr < 32; rr += 8)
        th[(long)(d0 + tj + rr) * CHN + i0 + ti] = f2h(tile[ti][tj + rr]);
}

// fused u-pad (f16) + dt (fp32 softplus A_t).  One block = 8 u-rows.
__global__ __launch_bounds__(256) void u_pad_dt(
    const float* __restrict__ u, const float* __restrict__ W1,
    const float* __restrict__ A_log, u16* __restrict__ ph, float* __restrict__ A_t)
{
    __shared__ float us[8][1024];
    int r0 = blockIdx.x * 8;
    int tid = threadIdx.x;
#pragma unroll
    for (int rep = 0; rep < 8; ++rep) {
        int idx = rep * 256 + tid;
        int i = idx >> 8, kx = (idx & 255) << 2;
        *(f32x4*)&us[i][kx] = *(const f32x4*)&u[(long)(r0 + i) * 1024 + kx];
    }
    __syncthreads();
#pragma unroll
    for (int rep = 0; rep < 8; ++rep) {
        int idx = rep * 256 + tid;
        int i = idx >> 8, kx = (idx & 255) << 2;
        int r = r0 + i;
        long prow = (long)(r >> 11) * PADR_U + 3 + (r & 2047);
        f32x4 v = *(const f32x4*)&us[i][kx];
        ushort4 h;
        h.x = f2h(v[0]); h.y = f2h(v[1]); h.z = f2h(v[2]); h.w = f2h(v[3]);
        *(ushort4*)&ph[prow * 1024 + kx] = h;
    }
    int row = tid >> 5;
    int hh = tid & 31;
    const float* wrow = W1 + (long)(4224 + hh) * 1024;
    f32x4 a4 = {0.f, 0.f, 0.f, 0.f};
#pragma unroll 4
    for (int k = 0; k < 1024; k += 4) {
        f32x4 a = *(const f32x4*)&us[row][k];
        f32x4 b = *(const f32x4*)&wrow[k];
        a4 += a * b;
    }
    float dt = a4[0] + a4[1] + a4[2] + a4[3];
    if (dt <= 20.f) dt = log1pf(__expf(dt));
    float At = dt * (-__expf(A_log[hh]));
    int r = r0 + row;
    int b = r >> 11, l = r & 2047;
    A_t[((long)(b * 32 + hh)) * 2048 + l] = At;
}

__global__ void zero_pad_u(u16* __restrict__ ph) {
    int t = blockIdx.x * 256 + threadIdx.x;
    if (t < 3 * 1024) {
        ph[t] = 0;
        ph[(long)PADR_U * 1024 + t] = 0;
    }
}

__global__ void cast2_f16(const float* __restrict__ a, u16* __restrict__ oa,
                          const float* __restrict__ b, u16* __restrict__ ob, int n4) {
    int idx = blockIdx.x * 256 + threadIdx.x;
    const float* src;
    u16* dst;
    if (idx < n4) { src = a; dst = oa; }
    else if (idx < 2 * n4) { idx -= n4; src = b; dst = ob; }
    else return;
    f32x4 v = *(const f32x4*)&src[(long)idx * 4];
    ushort4 h;
    h.x = f2h(v[0]); h.y = f2h(v[1]); h.z = f2h(v[2]); h.w = f2h(v[3]);
    *(ushort4*)&dst[(long)idx * 4] = h;
}

// ---------------- chunked SSD (bl = 128, c = 16) ----------------
// merged: blocks 0..1023 = csum chunk; blocks 1024..1055 = g_chunk
__global__ __launch_bounds__(256) void csum_g(
    float* A_t, float* __restrict__ Atot,
    const float* __restrict__ Cm, const float* __restrict__ Bm, float* __restrict__ G)
{
    if (blockIdx.x < 1024) {
        if (threadIdx.x >= 64) return;
        int bid = blockIdx.x;
        int lane = threadIdx.x;
        float* p = A_t + (long)bid * 128;
        float v0 = p[lane * 2], v1 = p[lane * 2 + 1];
        float s = v0 + v1;
        float t = s;
#pragma unroll
        for (int d = 1; d < 64; d <<= 1) {
            float o = __shfl_up(t, d);
            if (lane >= d) t += o;
        }
        float excl = t - s;
        p[lane * 2] = excl + v0;
        p[lane * 2 + 1] = excl + s;
        if (lane == 63) Atot[bid] = t;
        return;
    }
    __shared__ float CsT[128 * 33];
    __shared__ float BsT[128 * 33];
    const int bid = blockIdx.x - 1024;   // b*16 + c
    const int b = bid >> 4, c = bid & 15;
    const long rowbase = (long)b * 2048 + c * 128;
    const int tid = threadIdx.x;
    const int li = tid & 15, si = tid >> 4;
    const int l0 = li * 8, s0 = si * 8;
    float acc[8][8];
#pragma unroll
    for (int i = 0; i < 8; ++i)
#pragma unroll
        for (int j = 0; j < 8; ++j) acc[i][j] = 0.f;

    for (int kt = 0; kt < 2; ++kt) {
        __syncthreads();
#pragma unroll
        for (int t = 0; t < 16; ++t) {
            int idx = t * 256 + tid;
            int row = idx >> 5, k = idx & 31;
            CsT[row * 33 + k] = Cm[(rowbase + row) * 64 + kt * 32 + k];
            BsT[row * 33 + k] = Bm[(rowbase + row) * 64 + kt * 32 + k];
        }
        __syncthreads();
        for (int k = 0; k < 32; ++k) {
            float cv[8], bv[8];
#pragma unroll
            for (int i = 0; i < 8; ++i) cv[i] = CsT[(l0 + i) * 33 + k];
#pragma unroll
            for (int j = 0; j < 8; ++j) bv[j] = BsT[(s0 + j) * 33 + k];
#pragma unroll
            for (int i = 0; i < 8; ++i)
#pragma unroll
                for (int j = 0; j < 8; ++j) acc[i][j] += cv[i] * bv[j];
        }
    }
    float* gz = G + (long)bid * 16384;
#pragma unroll
    for (int i = 0; i < 8; ++i) {
        f32x4 o0 = {acc[i][0], acc[i][1], acc[i][2], acc[i][3]};
        f32x4 o1 = {acc[i][4], acc[i][5], acc[i][6], acc[i][7]};
        *(f32x4*)&gz[(l0 + i) * 128 + s0] = o0;
        *(f32x4*)&gz[(l0 + i) * 128 + s0 + 4] = o1;
    }
}

// per (b,h,c): Y_diag = (G∘exp(segsum))@X -> XY ; Sc[p,n] = sum_s X[s,p]·exp(T-cs[s])·B[s,n]
// (R13/R14-proven body: exp in dynamic inner loop, cl[] in registers)
__global__ __launch_bounds__(256) void ssd_diag_states(
    float* XY, const float* __restrict__ Bm, const float* __restrict__ G,
    const float* __restrict__ cs, const float* __restrict__ Atot, float* __restrict__ Sc)
{
    __shared__ float Xs[128 * 64];
    __shared__ float Gb[32 * 132];
    __shared__ float csL[128];
    __shared__ float dsL[128];
    const int bid = blockIdx.x;
    const int bh = bid >> 4, c = bid & 15;
    const int b = bh >> 5, h = bh & 31;
    const long rowbase = (long)b * 2048 + c * 128;
    const float* gz = G + (long)(b * 16 + c) * 16384;
    const float atot = Atot[bid];
    const int tid = threadIdx.x;

    if (tid < 128) csL[tid] = cs[(long)bh * 2048 + c * 128 + tid];
#pragma unroll
    for (int t = 0; t < 8; ++t) {
        int idx = t * 256 + tid;
        int row = idx >> 4, c4 = (idx & 15) << 2;
        *(f32x4*)&Xs[row * 64 + c4] = *(const f32x4*)&XY[(rowbase + row) * 2048 + h * 64 + c4];
    }
    __syncthreads();
    if (tid < 128) dsL[tid] = __expf(atot - csL[tid]);

    const int lg = tid & 31, pg = tid >> 5;
    const int l0 = lg * 4, p0 = pg * 8;
    float cl[4];
#pragma unroll
    for (int i = 0; i < 4; ++i) cl[i] = csL[l0 + i];
    float acc1[4][8];
#pragma unroll
    for (int i = 0; i < 4; ++i)
#pragma unroll
        for (int j = 0; j < 8; ++j) acc1[i][j] = 0.f;

    for (int st = 0; st < 4; ++st) {
        __syncthreads();
#pragma unroll
        for (int t = 0; t < 16; ++t) {
            int idx = t * 256 + tid;
            int l = idx >> 5, sq = idx & 31;
            Gb[sq * 132 + l] = gz[l * 128 + st * 32 + sq];
        }
        __syncthreads();
        for (int sq = 0; sq < 32; ++sq) {
            int s = st * 32 + sq;
            float css = csL[s];
            f32x4 x0 = *(const f32x4*)&Xs[s * 64 + p0];
            f32x4 x1 = *(const f32x4*)&Xs[s * 64 + p0 + 4];
#pragma unroll
            for (int i = 0; i < 4; ++i) {
                int l = l0 + i;
                float P = (s <= l) ? Gb[sq * 132 + l] * __expf(cl[i] - css) : 0.f;
                acc1[i][0] += P * x0[0]; acc1[i][1] += P * x0[1];
                acc1[i][2] += P * x0[2]; acc1[i][3] += P * x0[3];
                acc1[i][4] += P * x1[0]; acc1[i][5] += P * x1[1];
                acc1[i][6] += P * x1[2]; acc1[i][7] += P * x1[3];
            }
        }
    }

    const int pq = tid & 15, nq = tid >> 4;
    const int pp0 = pq * 4, nn0 = nq * 4;
    float acc2[4][4];
#pragma unroll
    for (int i = 0; i < 4; ++i)
#pragma unroll
        for (int j = 0; j < 4; ++j) acc2[i][j] = 0.f;
    for (int half = 0; half < 2; ++half) {
        __syncthreads();
#pragma unroll
        for (int t = 0; t < 4; ++t) {
            int idx = t * 256 + tid;
            int srow = idx >> 4, c4 = (idx & 15) << 2;
            *(f32x4*)&Gb[srow * 64 + c4] = *(const f32x4*)&Bm[(rowbase + half * 64 + srow) * 64 + c4];
        }
        __syncthreads();
        for (int ss = 0; ss < 64; ++ss) {
            int s = half * 64 + ss;
            float d = dsL[s];
            f32x4 xv = *(const f32x4*)&Xs[s * 64 + pp0];
            f32x4 bv = *(const f32x4*)&Gb[ss * 64 + nn0];
            float xd[4];
#pragma unroll
            for (int i = 0; i < 4; ++i) xd[i] = xv[i] * d;
#pragma unroll
            for (int i = 0; i < 4; ++i)
#pragma unroll
                for (int j = 0; j < 4; ++j) acc2[i][j] += xd[i] * bv[j];
        }
    }
    long scb = (long)bid * 4096;
#pragma unroll
    for (int i = 0; i < 4; ++i) {
        f32x4 o = {acc2[i][0], acc2[i][1], acc2[i][2], acc2[i][3]};
        *(f32x4*)&Sc[scb + (pp0 + i) * 64 + nn0] = o;
    }
#pragma unroll
    for (int i = 0; i < 4; ++i) {
        f32x4 y0 = {acc1[i][0], acc1[i][1], acc1[i][2], acc1[i][3]};
        f32x4 y1 = {acc1[i][4], acc1[i][5], acc1[i][6], acc1[i][7]};
        long yo = (rowbase + l0 + i) * 2048 + h * 64 + p0;
        *(f32x4*)&XY[yo] = y0;
        *(f32x4*)&XY[yo + 4] = y1;
    }
}

// chunk recurrence (in place): Sc[c] -> S_in[c].  grid 256: bh*4 + quarter
__global__ __launch_bounds__(256) void ssd_combine(float* Sc, const float* __restrict__ Atot)
{
    int bh = blockIdx.x >> 2;
    int q = blockIdx.x & 3;
    int tid = threadIdx.x;
    float run[4];
#pragma unroll
    for (int t = 0; t < 4; ++t) run[t] = 0.f;
    for (int c = 0; c < 16; ++c) {
        float e = __expf(Atot[bh * 16 + c]);
        long base = (long)(bh * 16 + c) * 4096 + q * 1024;
#pragma unroll
        for (int t = 0; t < 4; ++t) {
            long idx = base + t * 256 + tid;
            float tmp = Sc[idx];
            Sc[idx] = run[t];
            run[t] = e * run[t] + tmp;
        }
    }
}

// Y += exp(cs[l]) · C[l]·S_in[p]   per (b,h,c)
__global__ __launch_bounds__(256) void ssd_yoff(
    const float* __restrict__ Cm, const float* __restrict__ Sin,
    const float* __restrict__ cs, float* XY)
{
    __shared__ float Cs[128 * 66];
    __shared__ float St[64 * 68];
    __shared__ float csL[128];
    const int bid = blockIdx.x;
    const int bh = bid >> 4, c = bid & 15;
    const int b = bh >> 5, h = bh & 31;
    const long rowbase = (long)b * 2048 + c * 128;
    const int tid = threadIdx.x;

    if (tid < 128) csL[tid] = cs[(long)bh * 2048 + c * 128 + tid];
#pragma unroll
    for (int t = 0; t < 32; ++t) {
        int idx = t * 256 + tid;
        int row = idx >> 6, n = idx & 63;
        Cs[row * 66 + n] = Cm[(rowbase + row) * 64 + n];
    }
#pragma unroll
    for (int t = 0; t < 16; ++t) {
        int idx = t * 256 + tid;
        int p = idx >> 6, n = idx & 63;
        St[n * 68 + p] = Sin[(long)bid * 4096 + p * 64 + n];
    }
    __syncthreads();

    const int lg = tid & 31, pg = tid >> 5;
    const int l0 = lg * 4, p0 = pg * 8;
    float el[4];
#pragma unroll
    for (int i = 0; i < 4; ++i) el[i] = __expf(csL[l0 + i]);
    float acc[4][8];
#pragma unroll
    for (int i = 0; i < 4; ++i)
#pragma unroll
        for (int j = 0; j < 8; ++j) acc[i][j] = 0.f;

    for (int n = 0; n < 64; ++n) {
        float cv[4];
#pragma unroll
        for (int i = 0; i < 4; ++i) cv[i] = Cs[(l0 + i) * 66 + n];
        f32x4 s0 = *(const f32x4*)&St[n * 68 + p0];
        f32x4 s1 = *(const f32x4*)&St[n * 68 + p0 + 4];
#pragma unroll
        for (int i = 0; i < 4; ++i) {
            acc[i][0] += cv[i] * s0[0]; acc[i][1] += cv[i] * s0[1];
            acc[i][2] += cv[i] * s0[2]; acc[i][3] += cv[i] * s0[3];
            acc[i][4] += cv[i] * s1[0]; acc[i][5] += cv[i] * s1[1];
            acc[i][6] += cv[i] * s1[2]; acc[i][7] += cv[i] * s1[3];
        }
    }
#pragma unroll
    for (int i = 0; i < 4; ++i) {
        long yo = (rowbase + l0 + i) * 2048 + h * 64 + p0;
        f32x4 y0 = *(const f32x4*)&XY[yo];
        f32x4 y1 = *(const f32x4*)&XY[yo + 4];
        y0[0] += el[i] * acc[i][0]; y0[1] += el[i] * acc[i][1];
        y0[2] += el[i] * acc[i][2]; y0[3] += el[i] * acc[i][3];
        y1[0] += el[i] * acc[i][4]; y1[1] += el[i] * acc[i][5];
        y1[2] += el[i] * acc[i][6]; y1[3] += el[i] * acc[i][7];
        *(f32x4*)&XY[yo] = y0;
        *(f32x4*)&XY[yo + 4] = y1;
    }
}

// h = gelu(u2raw)*Y ; LayerNorm ; store hn (single f16)
__global__ __launch_bounds__(256) void ln_kernel(
    const float* __restrict__ u2raw, const float* __restrict__ Y,
    const float* __restrict__ lng, const float* __restrict__ lnb,
    u16* __restrict__ hh)
{
    __shared__ float hbuf[2048];
    __shared__ float rs[4], rs2[4];
    int r = blockIdx.x;
    int tid = threadIdx.x;
    float s = 0.f, s2 = 0.f;
    for (int j = tid; j < 2048; j += 256) {
        float x = u2raw[(long)r * 2048 + j];
        float g = 0.5f * x * (1.f + erff(x * 0.70710678118654752f));
        float hv = g * Y[(long)r * 2048 + j];
        hbuf[j] = hv;
        s += hv;
        s2 += hv * hv;
    }
    for (int d = 32; d > 0; d >>= 1) {
        s += __shfl_down(s, d);
        s2 += __shfl_down(s2, d);
    }
    if ((tid & 63) == 0) { rs[tid >> 6] = s; rs2[tid >> 6] = s2; }
    __syncthreads();
    float tot = rs[0] + rs[1] + rs[2] + rs[3];
    float tot2 = rs2[0] + rs2[1] + rs2[2] + rs2[3];
    float mu = tot * (1.f / 2048.f);
    float var = tot2 * (1.f / 2048.f) - mu * mu;
    float inv = rsqrtf(var + 1e-5f);
    for (int j = tid; j < 2048; j += 256) {
        float v = (hbuf[j] - mu) * inv * lng[j] + lnb[j];
        hh[(long)r * 2048 + j] = f2h(v);
    }
}

// ---------------- launcher ----------------
extern "C" void kernel_launch(void* const* d_in, const int* in_sizes, int n_in,
                              void* d_out, int out_size, void* d_ws, size_t ws_size,
                              hipStream_t stream) {
    const float* u = (const float*)d_in[0];
    const float* W1 = (const float*)d_in[1];
    const float* A_log = (const float*)d_in[2];
    const float* convw = (const float*)d_in[3];
    const float* convb = (const float*)d_in[4];
    const float* prelu = (const float*)d_in[5];
    const float* W2 = (const float*)d_in[6];
    const float* W3 = (const float*)d_in[7];
    const float* lng = (const float*)d_in[8];
    const float* lnb = (const float*)d_in[9];
    float* out = (float*)d_out;

    char* base = (char*)d_ws;
    size_t off = 0;
    auto nxt = [&](size_t bytes) -> char* {
        char* r = base + off;
        off = (off + bytes + 255) & ~(size_t)255;
        return r;
    };
    // ~130 MB total
    u16* cw_h = (u16*)nxt((size_t)4 * CHN * CHN * 2);      // 37.9MB, dead after W_eff
    float* u2raw = (float*)cw_h;                            // 33.6 <= 37.9 ✓ (GEMM2 after W_eff)
    u16* up_h = (u16*)nxt((size_t)2 * PADR_U * 1024 * 2);  // 8.40MB
    u16* w1t_h = (u16*)nxt((size_t)1024 * CHN * 2);        // 4.46MB ─┐ Gbuf aliases
    float* Gbuf = (float*)w1t_h;                            // 2.1MB  ─┘ (dead after W_eff)
    u16* wbig_h = (u16*)nxt((size_t)CHN * 4096 * 2);       // 17.83MB
    u16* w2_h = (u16*)nxt((size_t)DI * DM * 2);            // 4.19MB
    u16* w3_h = (u16*)nxt((size_t)DM * DI * 2);            // 4.19MB
    float* A_t = (float*)nxt((size_t)64 * 2048 * 4);       // 0.52MB (chunk csum in place)
    float* Atot = (float*)nxt((size_t)64 * 16 * 4);        // 4KB
    float* XY = (float*)nxt((size_t)ROWS * DI * 4);         // 33.55MB: X -> Y in place
    float* Bmat = (float*)nxt((size_t)ROWS * 64 * 4);      // 1.05MB
    float* Cmat = (float*)nxt((size_t)ROWS * 64 * 4);      // 1.05MB
    float* Sc = (float*)nxt((size_t)64 * 16 * 4096 * 4);   // 16.78MB, dead after yoff
    u16* hn_h = (u16*)Sc;                                   // 16.78MB == span ✓ (LN after yoff)

    // 1. prep
    conv_w_h<<<(CHN * CHN + 255) / 256, 256, 0, stream>>>(convw, cw_h);
    w1x_t<<<dim3(68, 32), 256, 0, stream>>>(W1, w1t_h);
    u_pad_dt<<<512, 256, 0, stream>>>(u, W1, A_log, up_h, A_t);
    zero_pad_u<<<12, 256, 0, stream>>>(up_h);
    cast2_f16<<<(2 * DI * DM / 4 + 255) / 256, 256, 0, stream>>>(
        W2, w2_h, W3, w3_h, DI * DM / 4);

    // 2. W_eff = convw @ W1x (single-f16), store f16 Wbig
    split_gemm<0, 3><<<dim3(68, 8), 256, 0, stream>>>(
        cw_h, w1t_h, nullptr, nullptr, nullptr, wbig_h,
        2176, 2176, 2176, 0, 0, nullptr, nullptr);

    // 3. conv: im2col over padded-u, K=4096 + bias + prelu + split
    split_gemm<1, 2><<<dim3(32, 17), 256, 0, stream>>>(
        up_h, wbig_h, XY, Bmat, Cmat, nullptr,
        4096, 0, 4096, 0, 0, convb, prelu);

    // 4. GEMM2: u2raw = u @ W_in2.T  (u2raw aliases cw_h — W_eff done)
    split_gemm<1, 0><<<dim3(32, 16), 256, 0, stream>>>(
        up_h, w2_h, u2raw, nullptr, nullptr, nullptr,
        1024, 0, 1024, 2048, 3, nullptr, nullptr);

    // 5. chunked SSD (fp32)
    csum_g<<<1056, 256, 0, stream>>>(A_t, Atot, Cmat, Bmat, Gbuf);
    ssd_diag_states<<<1024, 256, 0, stream>>>(XY, Bmat, Gbuf, A_t, Atot, Sc);
    ssd_combine<<<256, 256, 0, stream>>>(Sc, Atot);
    ssd_yoff<<<1024, 256, 0, stream>>>(Cmat, Sc, A_t, XY);

    // 6. h = gelu(u2raw)*Y ; LN -> single f16 hn (aliases Sc — dead)
    ln_kernel<<<4096, 256, 0, stream>>>(u2raw, XY, lng, lnb, hn_h);

    // 7. GEMM3: out = hn @ W_in3.T
    split_gemm<0, 0><<<dim3(32, 8), 256, 0, stream>>>(
        hn_h, w3_h, out, nullptr, nullptr, nullptr,
        2048, 2048, 2048, 1024, 0, nullptr, nullptr);
}